// Round 5
// baseline (76.860 us; speedup 1.0000x reference)
//
#include <hip/hip_runtime.h>
#include <hip/hip_bf16.h>

#define SIZE 128
#define NBLOCKS 4096

// var = e^b + 1/s, s = e^{-a} + e^{-lv};  inv_var = s/(e^b*s+1);
// sum(logvar) over a group = -log(prod inv_var)   [range-safe for groups of 4]
__device__ __forceinline__ void body4(float4 m, float4 lv, float4 tg,
                                      const float* __restrict__ ena,
                                      const float* __restrict__ eb,
                                      float& acc) {
    float prod = 1.0f;
    #pragma unroll
    for (int k = 0; k < 4; ++k) {
        float d   = (&m.x)[k] - (&tg.x)[k];
        float t   = __expf(-(&lv.x)[k]);               // v_exp_f32
        float s   = ena[k] + t;
        float u   = __builtin_fmaf(eb[k], s, 1.0f);
        float inv = s * __builtin_amdgcn_rcpf(u);      // v_rcp_f32
        acc  += d * d * inv;
        prod *= inv;
    }
    acc -= __logf(prod);                               // one log per 4 elems
}

__global__ __launch_bounds__(256) void probloss_partial(
    const float4* __restrict__ inputs,    // (N, 256): 64 float4/row
    const float4* __restrict__ targets,   // (N, 128): 32 float4/row
    const float4* __restrict__ maxlv,     // 32 float4
    const float4* __restrict__ minlv,     // 32 float4
    float* __restrict__ part,             // NBLOCKS partials
    int nrows)
{
    const int gtid    = blockIdx.x * blockDim.x + threadIdx.x;
    const int cg      = gtid & 31;        // fixed column group
    const int row0    = gtid >> 5;
    const int rstride = (gridDim.x * blockDim.x) >> 5;   // 32768 -> 8 iters

    float4 a = maxlv[cg];
    float4 b = minlv[cg];
    float ena[4], eb[4];
    #pragma unroll
    for (int k = 0; k < 4; ++k) {
        ena[k] = __expf(-(&a.x)[k]);
        eb[k]  = __expf((&b.x)[k]);
    }

    float acc = 0.0f;

    // 2-deep register software pipeline: loads for iter i+1 issue before
    // the trans-chain of iter i consumes its data.
    int r = row0;
    float4 m  = inputs[r * 64 + cg];
    float4 lv = inputs[r * 64 + 32 + cg];
    float4 tg = targets[r * 32 + cg];

    for (int rn = r + rstride; rn < nrows; rn += rstride) {
        float4 mN  = inputs[rn * 64 + cg];
        float4 lvN = inputs[rn * 64 + 32 + cg];
        float4 tgN = targets[rn * 32 + cg];
        body4(m, lv, tg, ena, eb, acc);
        m = mN; lv = lvN; tg = tgN;
    }
    body4(m, lv, tg, ena, eb, acc);        // epilogue

    // Wave-64 reduction
    #pragma unroll
    for (int off = 32; off > 0; off >>= 1)
        acc += __shfl_down(acc, off);

    __shared__ float smem[4];
    const int lane = threadIdx.x & 63;
    const int wid  = threadIdx.x >> 6;
    if (lane == 0) smem[wid] = acc;
    __syncthreads();
    if (threadIdx.x == 0)
        part[blockIdx.x] = smem[0] + smem[1] + smem[2] + smem[3];
}

__global__ __launch_bounds__(256) void probloss_final(
    const float4* __restrict__ part, float* __restrict__ out)
{
    float acc = 0.0f;
    for (int i = threadIdx.x; i < NBLOCKS / 4; i += 256) {
        float4 v = part[i];
        acc += (v.x + v.y) + (v.z + v.w);
    }
    #pragma unroll
    for (int off = 32; off > 0; off >>= 1)
        acc += __shfl_down(acc, off);

    __shared__ float smem[4];
    const int lane = threadIdx.x & 63;
    const int wid  = threadIdx.x >> 6;
    if (lane == 0) smem[wid] = acc;
    __syncthreads();
    if (threadIdx.x == 0)
        out[0] = smem[0] + smem[1] + smem[2] + smem[3];
}

extern "C" void kernel_launch(void* const* d_in, const int* in_sizes, int n_in,
                              void* d_out, int out_size, void* d_ws, size_t ws_size,
                              hipStream_t stream) {
    const float4* inputs  = (const float4*)d_in[0];
    const float4* targets = (const float4*)d_in[1];
    const float4* maxlv   = (const float4*)d_in[2];
    const float4* minlv   = (const float4*)d_in[3];
    float* out  = (float*)d_out;
    float* part = (float*)d_ws;

    const int nrows = in_sizes[1] / SIZE;      // N = 262144

    probloss_partial<<<NBLOCKS, 256, 0, stream>>>(inputs, targets, maxlv, minlv,
                                                  part, nrows);
    probloss_final<<<1, 256, 0, stream>>>((const float4*)part, out);
}